// Round 3
// baseline (990.200 us; speedup 1.0000x reference)
//
#include <hip/hip_runtime.h>
#include <stdint.h>

#define DX 1024
#define NB 64
#define DY 10
#define NJK 100

typedef unsigned short ushort_t;
typedef __attribute__((ext_vector_type(8))) short short8;
typedef __attribute__((ext_vector_type(4))) float f32x4;
typedef __attribute__((ext_vector_type(16))) float f32x16;

#define VMCNT2 asm volatile("s_waitcnt vmcnt(2)" ::: "memory")
#define VMCNT0 asm volatile("s_waitcnt vmcnt(0)" ::: "memory")
#define VMCNT4 asm volatile("s_waitcnt vmcnt(4)" ::: "memory")
#define VMCNT6 asm volatile("s_waitcnt vmcnt(6)" ::: "memory")
#define LGKM0 asm volatile("s_waitcnt lgkmcnt(0)" ::: "memory")

__device__ __forceinline__ unsigned short f2bf(float f) {
  unsigned int u = __builtin_bit_cast(unsigned int, f);
  u += 0x7fffu + ((u >> 16) & 1u);
  return (unsigned short)(u >> 16);
}
__device__ __forceinline__ float bf2f(unsigned short h) {
  unsigned int u = ((unsigned int)h) << 16;
  return __builtin_bit_cast(float, u);
}
__device__ __forceinline__ void gload16(const void* g, void* l) {
  __builtin_amdgcn_global_load_lds((const __attribute__((address_space(1))) unsigned int*)g,
                                   (__attribute__((address_space(3))) unsigned int*)l, 16, 0, 0);
}

// ---------------------------------------------------------------------------
// P0a: XtHL[b][p][KT(64)][slot(4)][8 bf16]: hi/lo split of X^T, slots
// PRE-PERMUTED: stored slot s holds logical slot s^(p&3)  (ls<2: hi chunk ls,
// ls>=2: lo chunk ls-2).  K1 stages this with linear global_load_lds.
// ---------------------------------------------------------------------------
__launch_bounds__(256)
__global__ void p0_transpose(const float* __restrict__ X, ushort_t* __restrict__ XtHL) {
  __shared__ float T[64][65];
  int blk = blockIdx.x;
  int b = blk >> 8;
  int tt = blk & 255;
  int r0 = (tt >> 4) << 6;  // k rows of X
  int c0 = (tt & 15) << 6;  // p cols of X
  const float* Xb = X + (size_t)b * DX * DX;
  int t = threadIdx.x;
  int r = t >> 4, c = t & 15;
#pragma unroll
  for (int s = 0; s < 4; ++s) {
    const float4 v = *(const float4*)(Xb + (size_t)(r0 + r + 16 * s) * DX + c0 + c * 4);
    T[r + 16 * s][c * 4 + 0] = v.x;
    T[r + 16 * s][c * 4 + 1] = v.y;
    T[r + 16 * s][c * 4 + 2] = v.z;
    T[r + 16 * s][c * 4 + 3] = v.w;
  }
  __syncthreads();
#pragma unroll
  for (int i = 0; i < 4; ++i) {
    int u = i * 256 + t;       // 0..1023
    int pl = u >> 4;           // local p
    int su = u & 15;
    int ktl = su >> 2;         // local k-tile (16k)
    int s = su & 3;            // stored slot
    int p = c0 + pl;
    int ls = s ^ (p & 3);      // logical slot
    int isLo = ls >> 1;
    int kc = ls & 1;
    unsigned short h[8];
#pragma unroll
    for (int e = 0; e < 8; ++e) {
      float x = T[ktl * 16 + kc * 8 + e][pl];
      unsigned short hh = f2bf(x);
      h[e] = isLo ? f2bf(x - bf2f(hh)) : hh;
    }
    size_t off = ((size_t)b * DX + p) * 2048 + (size_t)(r0 / 16 + ktl) * 32 + s * 8;
    uint4 v;
    v.x = (unsigned)h[0] | ((unsigned)h[1] << 16);
    v.y = (unsigned)h[2] | ((unsigned)h[3] << 16);
    v.z = (unsigned)h[4] | ((unsigned)h[5] << 16);
    v.w = (unsigned)h[6] | ((unsigned)h[7] << 16);
    *(uint4*)(XtHL + off) = v;
  }
}

// ---------------------------------------------------------------------------
// P0b: S[p][m] = sum_j rho[p][j][m][j]   (f32, 4 MiB)
// ---------------------------------------------------------------------------
__launch_bounds__(256)
__global__ void p0_sdiag(const float* __restrict__ rho, float* __restrict__ S) {
  int p = blockIdx.x;
  int t = threadIdx.x;
  const float* rp = rho + (size_t)p * (DY * DX * DY);
  float a0 = 0.f, a1 = 0.f, a2 = 0.f, a3 = 0.f;
#pragma unroll
  for (int j = 0; j < DY; ++j) {
    const float* base = rp + (size_t)j * (DX * DY) + j;
    a0 += base[(size_t)(4 * t + 0) * DY];
    a1 += base[(size_t)(4 * t + 1) * DY];
    a2 += base[(size_t)(4 * t + 2) * DY];
    a3 += base[(size_t)(4 * t + 3) * DY];
  }
  *(float4*)(S + (size_t)p * DX + 4 * t) = make_float4(a0, a1, a2, a3);
}

// ---------------------------------------------------------------------------
// K1: A[b]=X[b]@X[b], 3-pass split-bf16, counted-vmcnt 4-buffer pipeline.
// 256x256 tile, BK=16, 512 thr (8 waves 2Mx4N), 1 block/CU (128 KiB LDS).
// Per K-tile: VMCNT(2); write A(t+2); load f32A(t+3)+B gload(t+3);
//             ds_read 12 frags; lgkm0; setprio1; 24 MFMA; setprio0; barrier.
// ---------------------------------------------------------------------------
__launch_bounds__(512, 2)
__global__ void k1_gemm(const float* __restrict__ X,
                        const ushort_t* __restrict__ XtHL,
                        const float* __restrict__ S,
                        ushort_t* __restrict__ Ahg,
                        float* __restrict__ part_tr) {
  __shared__ ushort_t lds[65536];  // 4 bufs x (A 8192 | B 8192) ushorts
  int wg = blockIdx.x;
  int gt = (wg & 7) * 128 + (wg >> 3);  // XCD-chunked
  int b = gt >> 4;
  int tile = gt & 15;
  int m0 = (tile >> 2) << 8;
  int p0 = (tile & 3) << 8;
  int t = threadIdx.x;
  int wv = t >> 6, lane = t & 63, l31 = lane & 31, hi8 = lane >> 5;
  int wm = (wv >> 2) * 128, wp = (wv & 3) * 64;
  const float* Xb = X + (size_t)b * DX * DX;
  const ushort_t* Xt = XtHL + (size_t)b * DX * 2048;

  f32x16 acc[4][2];
#pragma unroll
  for (int mi = 0; mi < 4; ++mi)
#pragma unroll
    for (int ni = 0; ni < 2; ++ni)
#pragma unroll
      for (int e = 0; e < 16; ++e) acc[mi][ni][e] = 0.f;

  int arow = t >> 1, akh = t & 1;  // A staging role: 8 f32 at [arow][kt*16+akh*8]

  float4 sa, sb;        // stash: f32A for tile (t+3), consumed at iter t+1
  float4 pa0, pb0, pa1, pb1;  // prologue temps for A(0), A(1)

  auto loadA = [&](int kt, float4& ra, float4& rb) {
    const float* src = Xb + (size_t)(m0 + arow) * DX + kt * 16 + akh * 8;
    ra = *(const float4*)(src + 0);
    rb = *(const float4*)(src + 4);
  };
  auto writeA = [&](int buf, const float4& ra, const float4& rb) {
    float v[8] = {ra.x, ra.y, ra.z, ra.w, rb.x, rb.y, rb.z, rb.w};
    short8 ph, pl;
#pragma unroll
    for (int e = 0; e < 8; ++e) {
      unsigned short hh = f2bf(v[e]);
      ph[e] = (short)hh;
      pl[e] = (short)f2bf(v[e] - bf2f(hh));
    }
    int base = buf * 16384 + arow * 32;
    int sh = (akh ^ (arow & 3)) * 8;
    int sl = ((2 + akh) ^ (arow & 3)) * 8;
    *(short8*)&lds[base + sh] = ph;
    *(short8*)&lds[base + sl] = pl;
  };
  auto stageB = [&](int buf, int kt) {
#pragma unroll
    for (int i = 0; i < 2; ++i) {
      int u = i * 512 + t;
      int row = u >> 2, s = u & 3;
      const ushort_t* g = Xt + (size_t)(p0 + row) * 2048 + kt * 32 + s * 8;
      gload16(g, &lds[buf * 16384 + 8192 + (i * 512 + (t & ~63)) * 8]);
    }
  };

  // ---- prologue: stage tiles 0,1,2 ----
  loadA(0, pa0, pb0);
  loadA(1, pa1, pb1);
  loadA(2, sa, sb);
  stageB(0, 0);
  stageB(1, 1);
  stageB(2, 2);
  VMCNT4;  // all f32A + B(0) done; B(1),B(2) in flight
  writeA(0, pa0, pb0);
  writeA(1, pa1, pb1);
  LGKM0;
  __builtin_amdgcn_s_barrier();

#pragma unroll 1
  for (int kt = 0; kt < 64; ++kt) {
    int buf = kt & 3;
    // wait: B(kt+1) + f32A(kt+2) landed; B(kt+2) may stay in flight
    if (kt <= 61) { VMCNT2; } else if (kt == 62) { VMCNT0; }
    if (kt <= 61) writeA((kt + 2) & 3, sa, sb);
    if (kt <= 60) {
      loadA(kt + 3, sa, sb);
      stageB((kt + 3) & 3, kt + 3);
    }
    // frags
    short8 ah[4], al[4], bh[2], bl[2];
#pragma unroll
    for (int mi = 0; mi < 4; ++mi) {
      int m = wm + 32 * mi + l31;
      int base = buf * 16384 + m * 32;
      ah[mi] = *(const short8*)&lds[base + ((hi8 ^ (m & 3)) * 8)];
      al[mi] = *(const short8*)&lds[base + (((2 + hi8) ^ (m & 3)) * 8)];
    }
#pragma unroll
    for (int ni = 0; ni < 2; ++ni) {
      int p = wp + 32 * ni + l31;
      int base = buf * 16384 + 8192 + p * 32;
      bh[ni] = *(const short8*)&lds[base + ((hi8 ^ (p & 3)) * 8)];
      bl[ni] = *(const short8*)&lds[base + (((2 + hi8) ^ (p & 3)) * 8)];
    }
    LGKM0;
    __builtin_amdgcn_sched_barrier(0);
    __builtin_amdgcn_s_setprio(1);
#pragma unroll
    for (int mi = 0; mi < 4; ++mi)
#pragma unroll
      for (int ni = 0; ni < 2; ++ni) {
        acc[mi][ni] = __builtin_amdgcn_mfma_f32_32x32x16_bf16(ah[mi], bh[ni], acc[mi][ni], 0, 0, 0);
        acc[mi][ni] = __builtin_amdgcn_mfma_f32_32x32x16_bf16(ah[mi], bl[ni], acc[mi][ni], 0, 0, 0);
        acc[mi][ni] = __builtin_amdgcn_mfma_f32_32x32x16_bf16(al[mi], bh[ni], acc[mi][ni], 0, 0, 0);
      }
    __builtin_amdgcn_s_setprio(0);
    if (kt < 63) __builtin_amdgcn_s_barrier();
  }

  // ---- epilogue 1: trace partial from exact f32 accumulator ----
  float tracc = 0.f;
#pragma unroll
  for (int mi = 0; mi < 4; ++mi)
#pragma unroll
    for (int ni = 0; ni < 2; ++ni) {
      int p = p0 + wp + 32 * ni + l31;
#pragma unroll
      for (int rg = 0; rg < 4; ++rg) {
        int m = m0 + wm + 32 * mi + 8 * rg + 4 * hi8;
        const float4 sv = *(const float4*)(S + (size_t)p * DX + m);
        tracc += acc[mi][ni][rg * 4 + 0] * sv.x + acc[mi][ni][rg * 4 + 1] * sv.y +
                 acc[mi][ni][rg * 4 + 2] * sv.z + acc[mi][ni][rg * 4 + 3] * sv.w;
      }
    }
#pragma unroll
  for (int off = 32; off > 0; off >>= 1) tracc += __shfl_xor(tracc, off, 64);
  __syncthreads();
  if (lane == 0) ((float*)lds)[wv] = tracc;
  __syncthreads();
  if (t == 0) {
    float s = 0.f;
    for (int i = 0; i < 8; ++i) s += ((float*)lds)[i];
    part_tr[gt] = s;
  }
  __syncthreads();

  // ---- epilogue 2: Ah -> LDS [p][m] (swizzled) -> coalesced 16B stores ----
#pragma unroll
  for (int mi = 0; mi < 4; ++mi)
#pragma unroll
    for (int ni = 0; ni < 2; ++ni) {
      int p = wp + 32 * ni + l31;
#pragma unroll
      for (int rg = 0; rg < 4; ++rg) {
        int m = wm + 32 * mi + 8 * rg + 4 * hi8;
        unsigned int h0 = f2bf(acc[mi][ni][rg * 4 + 0]);
        unsigned int h1 = f2bf(acc[mi][ni][rg * 4 + 1]);
        unsigned int h2 = f2bf(acc[mi][ni][rg * 4 + 2]);
        unsigned int h3 = f2bf(acc[mi][ni][rg * 4 + 3]);
        int idx = p * 256 + (((m >> 3) ^ (p & 7)) << 3) + (m & 7);
        *(uint2*)&lds[idx] = make_uint2(h0 | (h1 << 16), h2 | (h3 << 16));
      }
    }
  __syncthreads();
#pragma unroll
  for (int i = 0; i < 16; ++i) {
    int cc = i * 512 + t;
    int row = cc >> 5, sl = cc & 31;
    int idx = row * 256 + ((sl ^ (row & 7)) << 3);
    uint4 v = *(const uint4*)&lds[idx];
    *(uint4*)(Ahg + ((size_t)(p0 + row) * NB + b) * DX + m0 + sl * 8) = v;
  }
}

// ---------------------------------------------------------------------------
// K2: numerator only. One block per p: C[b,jk] += Ah[b,m]*R[m,jk], K=1024.
// 4-bit slot swizzle (&15) for conflict-free 16-slot rows.
// ---------------------------------------------------------------------------
__launch_bounds__(256)
__global__ void k2_contract(const float* __restrict__ rho,
                            const ushort_t* __restrict__ Ahg,
                            float* __restrict__ part_rho) {
  __shared__ ushort_t Ah_s[8192];       // 64 b x 128 m
  __shared__ ushort_t R_s[112 * 128];   // rows jk (100 used), cols m
  int p = blockIdx.x;
  int t = threadIdx.x;
  int wv = t >> 6, lane = t & 63, lr = lane & 15, lg = lane >> 4;
  const float* rp = rho + (size_t)p * (DY * DX * DY);
  const ushort_t* Ahp = Ahg + (size_t)p * (NB * DX);

  f32x4 acc[7];
#pragma unroll
  for (int n = 0; n < 7; ++n)
#pragma unroll
    for (int i = 0; i < 4; ++i) acc[n][i] = 0.f;

  for (int mc = 0; mc < 8; ++mc) {
    __syncthreads();
#pragma unroll
    for (int i = 0; i < 4; ++i) {
      int c = i * 256 + t;
      int br = c >> 4, psl = c & 15;
      int lsl = psl ^ (br & 15);
      const ushort_t* g = Ahp + (size_t)br * DX + mc * 128 + lsl * 8;
      int wb = i * 256 + (t & ~63);
      gload16(g, &Ah_s[wb * 8]);
    }
    for (int u = t; u < 6400; u += 256) {
      int j = u / 640;
      int rem = u - j * 640;
      int m = rem / 5;
      int kp = (rem - m * 5) * 2;
      const float2 v = *(const float2*)(rp + (size_t)j * (DX * DY) + (size_t)(mc * 128 + m) * DY + kp);
      int row0 = j * DY + kp;
      R_s[(row0 * 128 + m) ^ ((row0 & 15) << 3)] = f2bf(v.x);
      int row1 = row0 + 1;
      R_s[(row1 * 128 + m) ^ ((row1 & 15) << 3)] = f2bf(v.y);
    }
    __syncthreads();
#pragma unroll
    for (int s = 0; s < 4; ++s) {
      int kk = s * 32 + lg * 8;
      int ra = 16 * wv + lr;
      short8 af = *(const short8*)&Ah_s[(ra * 128 + kk) ^ ((ra & 15) << 3)];
#pragma unroll
      for (int n = 0; n < 7; ++n) {
        int rb = 16 * n + lr;
        short8 bf = *(const short8*)&R_s[(rb * 128 + kk) ^ ((rb & 15) << 3)];
        acc[n] = __builtin_amdgcn_mfma_f32_16x16x32_bf16(af, bf, acc[n], 0, 0, 0);
      }
    }
  }
#pragma unroll
  for (int n = 0; n < 7; ++n) {
    int col = 16 * n + lr;
    if (col < NJK) {
#pragma unroll
      for (int i = 0; i < 4; ++i) {
        int b_ = 16 * wv + lg * 4 + i;
        part_rho[((size_t)p * NB + b_) * NJK + col] = acc[n][i];
      }
    }
  }
}

// ---------------------------------------------------------------------------
// K3a: partial p-reduction of numerator; K3b: finish + divide by trace.
// ---------------------------------------------------------------------------
__launch_bounds__(128)
__global__ void k3a(const float* __restrict__ part_rho, float* __restrict__ ws2) {
  int blk = blockIdx.x;  // 128 = 64 b x 2 halves
  int b = blk >> 1, h = blk & 1;
  int t = threadIdx.x;
  if (t >= NJK) return;
  float s = 0.f;
  for (int pp = 0; pp < 512; ++pp)
    s += part_rho[((size_t)(h * 512 + pp) * NB + b) * NJK + t];
  ws2[(size_t)(h * NB + b) * 128 + t] = s;
}

__launch_bounds__(128)
__global__ void k3b(const float* __restrict__ ws2, const float* __restrict__ part_tr,
                    float* __restrict__ out) {
  int b = blockIdx.x;
  int t = threadIdx.x;
  float tr = 0.f;
#pragma unroll
  for (int i = 0; i < 16; ++i) tr += part_tr[b * 16 + i];
  if (t < NJK) {
    float v = ws2[(size_t)b * 128 + t] + ws2[(size_t)(NB + b) * 128 + t];
    out[b * NJK + t] = v / tr;
  }
}

extern "C" void kernel_launch(void* const* d_in, const int* in_sizes, int n_in,
                              void* d_out, int out_size, void* d_ws, size_t ws_size,
                              hipStream_t stream) {
  const float* X = (const float*)d_in[0];
  const float* rho = (const float*)d_in[1];
  float* out = (float*)d_out;
  char* ws = (char*)d_ws;

  const size_t MB = 1048576ull;
  ushort_t* XtHL = (ushort_t*)(ws);                 // 256 MiB
  ushort_t* Ahg = (ushort_t*)(ws + 256 * MB);       // 128 MiB
  float* S = (float*)(ws + 384 * MB);               // 4 MiB
  float* part_tr = (float*)(ws + 388 * MB);         // 4 KiB
  float* part_rho = (float*)(ws);                   // overlays XtHL (dead after K1)
  float* ws2 = (float*)(ws + 32 * MB);              // overlays XtHL tail
  size_t need = 388 * MB + 65536;
  if (ws_size < need) return;

  hipLaunchKernelGGL(p0_transpose, dim3(16384), dim3(256), 0, stream, X, XtHL);
  hipLaunchKernelGGL(p0_sdiag, dim3(1024), dim3(256), 0, stream, rho, S);
  hipLaunchKernelGGL(k1_gemm, dim3(1024), dim3(512), 0, stream, X, XtHL, S, Ahg, part_tr);
  hipLaunchKernelGGL(k2_contract, dim3(1024), dim3(256), 0, stream, rho, Ahg, part_rho);
  hipLaunchKernelGGL(k3a, dim3(128), dim3(128), 0, stream, part_rho, ws2);
  hipLaunchKernelGGL(k3b, dim3(64), dim3(128), 0, stream, ws2, part_tr, out);
}

// Round 5
// 890.834 us; speedup vs baseline: 1.1115x; 1.1115x over previous
//
#include <hip/hip_runtime.h>
#include <stdint.h>

#define DX 1024
#define NB 64
#define DY 10
#define NJK 100

typedef unsigned short ushort_t;
typedef __attribute__((ext_vector_type(8))) short short8;
typedef __attribute__((ext_vector_type(4))) float f32x4;
typedef __attribute__((ext_vector_type(16))) float f32x16;

#define VMCNT8 asm volatile("s_waitcnt vmcnt(8)" ::: "memory")
#define VMCNT0 asm volatile("s_waitcnt vmcnt(0)" ::: "memory")
#define CFENCE asm volatile("" ::: "memory")

__device__ __forceinline__ unsigned short f2bf(float f) {
  unsigned int u = __builtin_bit_cast(unsigned int, f);
  u += 0x7fffu + ((u >> 16) & 1u);
  return (unsigned short)(u >> 16);
}
__device__ __forceinline__ float bf2f(unsigned short h) {
  unsigned int u = ((unsigned int)h) << 16;
  return __builtin_bit_cast(float, u);
}
__device__ __forceinline__ void gload16(const void* g, void* l) {
  __builtin_amdgcn_global_load_lds((const __attribute__((address_space(1))) unsigned int*)g,
                                   (__attribute__((address_space(3))) unsigned int*)l, 16, 0, 0);
}

// ---------------------------------------------------------------------------
// P0a: for one 16-batch group, emit BOTH operands of K1 pre-split:
//  XHL [bl][kt(32)][m(1024)][8 slots x 16B] : record = [Ah k0..31 | Al k0..31]
//  XtHL[bl][kt(32)][p(1024)][8 slots x 16B] : same for X^T rows.
// ---------------------------------------------------------------------------
__launch_bounds__(256)
__global__ void p0_split(const float* __restrict__ X,
                         ushort_t* __restrict__ XHL, ushort_t* __restrict__ XtHL) {
  __shared__ float T[64][65];
  int blk = blockIdx.x;
  int bl = blk >> 8;  // local batch 0..15
  int tt = blk & 255;
  int r0 = (tt >> 4) << 6;  // X row block
  int c0 = (tt & 15) << 6;  // X col block
  const float* Xb = X + (size_t)bl * DX * DX;
  int t = threadIdx.x;
  int r = t >> 4, c = t & 15;
#pragma unroll
  for (int s = 0; s < 4; ++s) {
    const float4 v = *(const float4*)(Xb + (size_t)(r0 + r + 16 * s) * DX + c0 + c * 4);
    T[r + 16 * s][c * 4 + 0] = v.x;
    T[r + 16 * s][c * 4 + 1] = v.y;
    T[r + 16 * s][c * 4 + 2] = v.z;
    T[r + 16 * s][c * 4 + 3] = v.w;
  }
  __syncthreads();
  int s8 = t & 7;   // slot 0..7
  int rw = t >> 3;  // 0..31
  int isLo = s8 >> 2, q = s8 & 3;
#pragma unroll
  for (int ktl = 0; ktl < 2; ++ktl) {
#pragma unroll
    for (int sp = 0; sp < 2; ++sp) {
      int loc = rw + sp * 32;
      {
        unsigned short h[8];
#pragma unroll
        for (int e = 0; e < 8; ++e) {
          float x = T[loc][ktl * 32 + q * 8 + e];
          unsigned short hh = f2bf(x);
          h[e] = isLo ? f2bf(x - bf2f(hh)) : hh;
        }
        int kt = (c0 >> 5) + ktl;
        size_t off = (((size_t)bl * 32 + kt) * 1024 + (r0 + loc)) * 64 + s8 * 8;
        uint4 v;
        v.x = (unsigned)h[0] | ((unsigned)h[1] << 16);
        v.y = (unsigned)h[2] | ((unsigned)h[3] << 16);
        v.z = (unsigned)h[4] | ((unsigned)h[5] << 16);
        v.w = (unsigned)h[6] | ((unsigned)h[7] << 16);
        *(uint4*)(XHL + off) = v;
      }
      {
        unsigned short h[8];
#pragma unroll
        for (int e = 0; e < 8; ++e) {
          float x = T[ktl * 32 + q * 8 + e][loc];
          unsigned short hh = f2bf(x);
          h[e] = isLo ? f2bf(x - bf2f(hh)) : hh;
        }
        int kt = (r0 >> 5) + ktl;
        size_t off = (((size_t)bl * 32 + kt) * 1024 + (c0 + loc)) * 64 + s8 * 8;
        uint4 v;
        v.x = (unsigned)h[0] | ((unsigned)h[1] << 16);
        v.y = (unsigned)h[2] | ((unsigned)h[3] << 16);
        v.z = (unsigned)h[4] | ((unsigned)h[5] << 16);
        v.w = (unsigned)h[6] | ((unsigned)h[7] << 16);
        *(uint4*)(XtHL + off) = v;
      }
    }
  }
}

// ---------------------------------------------------------------------------
// P0b: S[p][m] = sum_j rho[p][j][m][j]   (f32, 4 MiB) — exact-trace input.
// ---------------------------------------------------------------------------
__launch_bounds__(256)
__global__ void p0_sdiag(const float* __restrict__ rho, float* __restrict__ S) {
  int p = blockIdx.x;
  int t = threadIdx.x;
  const float* rp = rho + (size_t)p * (DY * DX * DY);
  float a0 = 0.f, a1 = 0.f, a2 = 0.f, a3 = 0.f;
#pragma unroll
  for (int j = 0; j < DY; ++j) {
    const float* base = rp + (size_t)j * (DX * DY) + j;
    a0 += base[(size_t)(4 * t + 0) * DY];
    a1 += base[(size_t)(4 * t + 1) * DY];
    a2 += base[(size_t)(4 * t + 2) * DY];
    a3 += base[(size_t)(4 * t + 3) * DY];
  }
  *(float4*)(S + (size_t)p * DX + 4 * t) = make_float4(a0, a1, a2, a3);
}

// ---------------------------------------------------------------------------
// K1: A[b]=X[b]@X[b], 3-pass split-bf16. 256x256 tile, BK=32, 8 waves (2x4),
// all staging via global_load_lds (front-loaded 8/thread/kt), counted
// vmcnt(8), raw barriers (no drain), setprio MFMA clusters.
// Epilogue 1: EXACT trace partial = <f32 acc, S[p,m]> -> part_tr[b*16+tile].
// Epilogue 2: Ah bf16 -> [p][b][m] via LDS transpose (coalesced).
// ---------------------------------------------------------------------------
__launch_bounds__(512, 2)
__global__ void k1_gemm(const ushort_t* __restrict__ XHL,
                        const ushort_t* __restrict__ XtHL,
                        const float* __restrict__ S,
                        ushort_t* __restrict__ Ahg,
                        float* __restrict__ part_tr, int bg) {
  __shared__ ushort_t lds[65536];  // 2 bufs x (A 16384 | B 16384) ushorts
  int wg = blockIdx.x;
  int gt = (wg & 7) * 32 + (wg >> 3);  // XCD-chunked: 2 batches per XCD
  int bl = gt >> 4, tile = gt & 15;
  int b = bg * 16 + bl;
  int m0 = (tile >> 2) << 8, p0 = (tile & 3) << 8;
  int t = threadIdx.x;
  int wv = t >> 6, lane = t & 63, l31 = lane & 31, hi8 = lane >> 5;
  int wm = (wv >> 2) << 7, wp = (wv & 3) << 6;

  f32x16 acc[4][2];
#pragma unroll
  for (int mi = 0; mi < 4; ++mi)
#pragma unroll
    for (int ni = 0; ni < 2; ++ni)
#pragma unroll
      for (int e = 0; e < 16; ++e) acc[mi][ni][e] = 0.f;

  int lam = lane >> 3;          // row-within-8
  int lsl = (lane & 7) ^ lam;   // inverse-swizzled source slot
  const ushort_t* Asrc = XHL + ((size_t)bl * 32 * 1024 + m0) * 64 + (size_t)lsl * 8;
  const ushort_t* Bsrc = XtHL + ((size_t)bl * 32 * 1024 + p0) * 64 + (size_t)lsl * 8;
  int ldsw = (t & ~63) * 8;  // wave-uniform ushort offset (wv*512)

  auto stage = [&](int kt) {
    int buf = (kt & 1) << 15;
    size_t ko = (size_t)kt * 65536;
#pragma unroll
    for (int i = 0; i < 4; ++i) {
      int rr = (i << 6) + (wv << 3) + lam;
      gload16(Asrc + ko + (size_t)rr * 64, &lds[buf + (i << 12) + ldsw]);
    }
#pragma unroll
    for (int i = 0; i < 4; ++i) {
      int rr = (i << 6) + (wv << 3) + lam;
      gload16(Bsrc + ko + (size_t)rr * 64, &lds[buf + 16384 + (i << 12) + ldsw]);
    }
  };

  stage(0);
#pragma unroll 1
  for (int kt = 0; kt < 32; ++kt) {
    int buf = (kt & 1) << 15;
    if (kt < 31) {
      stage(kt + 1);
      VMCNT8;
    } else {
      VMCNT0;
    }
    __builtin_amdgcn_s_barrier();
    CFENCE;
#pragma unroll
    for (int kc = 0; kc < 2; ++kc) {
      short8 bh[2], blo[2];
#pragma unroll
      for (int ni = 0; ni < 2; ++ni) {
        int p = wp + (ni << 5) + l31;
        int rowb = buf + 16384 + p * 64;
        bh[ni] = *(const short8*)&lds[rowb + (((kc * 2 + hi8) ^ (p & 7)) << 3)];
        blo[ni] = *(const short8*)&lds[rowb + (((4 + kc * 2 + hi8) ^ (p & 7)) << 3)];
      }
#pragma unroll
      for (int mh = 0; mh < 2; ++mh) {
        short8 ah[2], al[2];
#pragma unroll
        for (int mi2 = 0; mi2 < 2; ++mi2) {
          int m = wm + ((mh * 2 + mi2) << 5) + l31;
          int rowa = buf + m * 64;
          ah[mi2] = *(const short8*)&lds[rowa + (((kc * 2 + hi8) ^ (m & 7)) << 3)];
          al[mi2] = *(const short8*)&lds[rowa + (((4 + kc * 2 + hi8) ^ (m & 7)) << 3)];
        }
        __builtin_amdgcn_s_setprio(1);
#pragma unroll
        for (int mi2 = 0; mi2 < 2; ++mi2) {
          int mi = mh * 2 + mi2;
#pragma unroll
          for (int ni = 0; ni < 2; ++ni) {
            acc[mi][ni] = __builtin_amdgcn_mfma_f32_32x32x16_bf16(ah[mi2], bh[ni], acc[mi][ni], 0, 0, 0);
            acc[mi][ni] = __builtin_amdgcn_mfma_f32_32x32x16_bf16(ah[mi2], blo[ni], acc[mi][ni], 0, 0, 0);
            acc[mi][ni] = __builtin_amdgcn_mfma_f32_32x32x16_bf16(al[mi2], bh[ni], acc[mi][ni], 0, 0, 0);
          }
        }
        __builtin_amdgcn_s_setprio(0);
      }
    }
    CFENCE;
    __builtin_amdgcn_s_barrier();
  }

  // ---- epilogue 1: EXACT trace partial from f32 accumulator ----
  float tracc = 0.f;
#pragma unroll
  for (int mi = 0; mi < 4; ++mi)
#pragma unroll
    for (int ni = 0; ni < 2; ++ni) {
      int p = p0 + wp + (ni << 5) + l31;
#pragma unroll
      for (int rg = 0; rg < 4; ++rg) {
        int m = m0 + wm + (mi << 5) + 8 * rg + 4 * hi8;
        const float4 sv = *(const float4*)(S + (size_t)p * DX + m);
        tracc += acc[mi][ni][rg * 4 + 0] * sv.x + acc[mi][ni][rg * 4 + 1] * sv.y +
                 acc[mi][ni][rg * 4 + 2] * sv.z + acc[mi][ni][rg * 4 + 3] * sv.w;
      }
    }
#pragma unroll
  for (int off = 32; off > 0; off >>= 1) tracc += __shfl_xor(tracc, off, 64);
  __syncthreads();
  if (lane == 0) ((float*)lds)[wv] = tracc;
  __syncthreads();
  if (t == 0) {
    float s = 0.f;
    for (int i = 0; i < 8; ++i) s += ((float*)lds)[i];
    part_tr[b * 16 + tile] = s;
  }
  __syncthreads();

  // ---- epilogue 2: Ah -> LDS [p][m] (swizzled) -> coalesced 16B stores ----
#pragma unroll
  for (int mi = 0; mi < 4; ++mi)
#pragma unroll
    for (int ni = 0; ni < 2; ++ni) {
      int p = wp + (ni << 5) + l31;
#pragma unroll
      for (int rg = 0; rg < 4; ++rg) {
        int m = wm + (mi << 5) + 8 * rg + 4 * hi8;
        unsigned int h0 = f2bf(acc[mi][ni][rg * 4 + 0]);
        unsigned int h1 = f2bf(acc[mi][ni][rg * 4 + 1]);
        unsigned int h2 = f2bf(acc[mi][ni][rg * 4 + 2]);
        unsigned int h3 = f2bf(acc[mi][ni][rg * 4 + 3]);
        int idx = p * 256 + (((m >> 3) ^ (p & 7)) << 3) + (m & 7);
        *(uint2*)&lds[idx] = make_uint2(h0 | (h1 << 16), h2 | (h3 << 16));
      }
    }
  __syncthreads();
#pragma unroll
  for (int i = 0; i < 16; ++i) {
    int cc = i * 512 + t;
    int row = cc >> 5, sl = cc & 31;
    int idx = row * 256 + ((sl ^ (row & 7)) << 3);
    uint4 v = *(const uint4*)&lds[idx];
    *(uint4*)(Ahg + ((size_t)(p0 + row) * NB + b) * DX + m0 + sl * 8) = v;
  }
}

// ---------------------------------------------------------------------------
// K2: numerator. One block per p: C[b,jk] += Ah[b,m]*R[m,jk], K=1024.
// ---------------------------------------------------------------------------
__launch_bounds__(256)
__global__ void k2_contract(const float* __restrict__ rho,
                            const ushort_t* __restrict__ Ahg,
                            float* __restrict__ part_rho) {
  __shared__ ushort_t Ah_s[8192];      // 64 b x 128 m
  __shared__ ushort_t R_s[112 * 128];  // rows jk (100 used), cols m
  int p = blockIdx.x;
  int t = threadIdx.x;
  int wv = t >> 6, lane = t & 63, lr = lane & 15, lg = lane >> 4;
  const float* rp = rho + (size_t)p * (DY * DX * DY);
  const ushort_t* Ahp = Ahg + (size_t)p * (NB * DX);

  f32x4 acc[7];
#pragma unroll
  for (int n = 0; n < 7; ++n)
#pragma unroll
    for (int i = 0; i < 4; ++i) acc[n][i] = 0.f;

  for (int mc = 0; mc < 8; ++mc) {
    __syncthreads();
#pragma unroll
    for (int i = 0; i < 4; ++i) {
      int c = i * 256 + t;
      int br = c >> 4, psl = c & 15;
      int lsl = psl ^ (br & 15);
      const ushort_t* g = Ahp + (size_t)br * DX + mc * 128 + lsl * 8;
      int wb = i * 256 + (t & ~63);
      gload16(g, &Ah_s[wb * 8]);
    }
    for (int u = t; u < 6400; u += 256) {
      int j = u / 640;
      int rem = u - j * 640;
      int m = rem / 5;
      int kp = (rem - m * 5) * 2;
      const float2 v = *(const float2*)(rp + (size_t)j * (DX * DY) + (size_t)(mc * 128 + m) * DY + kp);
      int row0 = j * DY + kp;
      R_s[(row0 * 128 + m) ^ ((row0 & 15) << 3)] = f2bf(v.x);
      int row1 = row0 + 1;
      R_s[(row1 * 128 + m) ^ ((row1 & 15) << 3)] = f2bf(v.y);
    }
    __syncthreads();
#pragma unroll
    for (int s = 0; s < 4; ++s) {
      int kk = s * 32 + lg * 8;
      int ra = 16 * wv + lr;
      short8 af = *(const short8*)&Ah_s[(ra * 128 + kk) ^ ((ra & 15) << 3)];
      __builtin_amdgcn_s_setprio(1);
#pragma unroll
      for (int n = 0; n < 7; ++n) {
        int rb = 16 * n + lr;
        short8 bf = *(const short8*)&R_s[(rb * 128 + kk) ^ ((rb & 15) << 3)];
        acc[n] = __builtin_amdgcn_mfma_f32_16x16x32_bf16(af, bf, acc[n], 0, 0, 0);
      }
      __builtin_amdgcn_s_setprio(0);
    }
  }
#pragma unroll
  for (int n = 0; n < 7; ++n) {
    int col = 16 * n + lr;
    if (col < NJK) {
#pragma unroll
      for (int i = 0; i < 4; ++i) {
        int b_ = 16 * wv + lg * 4 + i;
        part_rho[((size_t)p * NB + b_) * NJK + col] = acc[n][i];
      }
    }
  }
}

// ---------------------------------------------------------------------------
// K3a: partial p-reduction; K3b: finish + divide by EXACT trace.
// ---------------------------------------------------------------------------
__launch_bounds__(128)
__global__ void k3a(const float* __restrict__ part_rho, float* __restrict__ ws2) {
  int blk = blockIdx.x;  // 128 = 64 b x 2 halves
  int b = blk >> 1, h = blk & 1;
  int t = threadIdx.x;
  if (t >= NJK) return;
  float s = 0.f;
  for (int pp = 0; pp < 512; ++pp)
    s += part_rho[((size_t)(h * 512 + pp) * NB + b) * NJK + t];
  ws2[(size_t)(h * NB + b) * 128 + t] = s;
}

__launch_bounds__(128)
__global__ void k3b(const float* __restrict__ ws2, const float* __restrict__ part_tr,
                    float* __restrict__ out) {
  int b = blockIdx.x;
  int t = threadIdx.x;
  float tr = 0.f;
#pragma unroll
  for (int i = 0; i < 16; ++i) tr += part_tr[b * 16 + i];
  if (t < NJK) {
    float v = ws2[(size_t)b * 128 + t] + ws2[(size_t)(NB + b) * 128 + t];
    out[b * NJK + t] = v / tr;
  }
}

extern "C" void kernel_launch(void* const* d_in, const int* in_sizes, int n_in,
                              void* d_out, int out_size, void* d_ws, size_t ws_size,
                              hipStream_t stream) {
  const float* X = (const float*)d_in[0];
  const float* rho = (const float*)d_in[1];
  float* out = (float*)d_out;
  char* ws = (char*)d_ws;

  const size_t MB = 1048576ull;
  ushort_t* XHL = (ushort_t*)(ws);              // 64 MiB (per 16-batch group)
  ushort_t* XtHL = (ushort_t*)(ws + 64 * MB);   // 64 MiB
  ushort_t* Ahg = (ushort_t*)(ws + 128 * MB);   // 128 MiB
  float* S = (float*)(ws + 256 * MB);           // 4 MiB
  float* part_tr = (float*)(ws + 260 * MB);     // 4 KiB
  float* part_rho = (float*)(ws);               // 25 MiB, overlays XHL (dead after K1s)
  float* ws2 = (float*)(ws + 32 * MB);          // 64 KiB, past part_rho
  size_t need = 260 * MB + 65536;
  if (ws_size < need) return;

  hipLaunchKernelGGL(p0_sdiag, dim3(1024), dim3(256), 0, stream, rho, S);
  for (int g = 0; g < 4; ++g) {
    hipLaunchKernelGGL(p0_split, dim3(4096), dim3(256), 0, stream,
                       X + (size_t)g * 16 * DX * DX, XHL, XtHL);
    hipLaunchKernelGGL(k1_gemm, dim3(256), dim3(512), 0, stream, XHL, XtHL, S, Ahg, part_tr, g);
  }
  hipLaunchKernelGGL(k2_contract, dim3(1024), dim3(256), 0, stream, rho, Ahg, part_rho);
  hipLaunchKernelGGL(k3a, dim3(128), dim3(128), 0, stream, part_rho, ws2);
  hipLaunchKernelGGL(k3b, dim3(64), dim3(128), 0, stream, ws2, part_tr, out);
}

// Round 6
// 821.613 us; speedup vs baseline: 1.2052x; 1.0842x over previous
//
#include <hip/hip_runtime.h>
#include <stdint.h>

#define DX 1024
#define NB 64
#define DY 10
#define NJK 100

typedef unsigned short ushort_t;
typedef __attribute__((ext_vector_type(8))) short short8;
typedef __attribute__((ext_vector_type(4))) float f32x4;
typedef __attribute__((ext_vector_type(16))) float f32x16;

#define VMCNT11 asm volatile("s_waitcnt vmcnt(11)" ::: "memory")
#define VMCNT8 asm volatile("s_waitcnt vmcnt(8)" ::: "memory")
#define VMCNT0 asm volatile("s_waitcnt vmcnt(0)" ::: "memory")
#define CFENCE asm volatile("" ::: "memory")

__device__ __forceinline__ unsigned short f2bf(float f) {
  unsigned int u = __builtin_bit_cast(unsigned int, f);
  u += 0x7fffu + ((u >> 16) & 1u);
  return (unsigned short)(u >> 16);
}
__device__ __forceinline__ float bf2f(unsigned short h) {
  unsigned int u = ((unsigned int)h) << 16;
  return __builtin_bit_cast(float, u);
}
__device__ __forceinline__ void gload16(const void* g, void* l) {
  __builtin_amdgcn_global_load_lds((const __attribute__((address_space(1))) unsigned int*)g,
                                   (__attribute__((address_space(3))) unsigned int*)l, 16, 0, 0);
}

// ---------------------------------------------------------------------------
// P0rho: one pass over rho per p:
//   R2[p][jk(112 pad)][mc(8)][slot(16)][8 bf16]  (plain slots, 224 MiB)
//   S[p][m] = sum_j rho[p][j][m][j]              (f32, fused diagonal)
// ---------------------------------------------------------------------------
__launch_bounds__(256)
__global__ void p0_rho(const float* __restrict__ rho, ushort_t* __restrict__ R2,
                       float* __restrict__ S) {
  __shared__ ushort_t R_s[112 * 128];
  __shared__ float S_s[128];
  int p = blockIdx.x;
  int t = threadIdx.x;
  const float* rp = rho + (size_t)p * (DY * DX * DY);
  ushort_t* R2p = R2 + (size_t)p * (112 * 1024);

  for (int mc = 0; mc < 8; ++mc) {
    __syncthreads();  // previous chunk's readback complete
    if (t < 128) S_s[t] = 0.f;
    __syncthreads();
    for (int u = t; u < 6400; u += 256) {
      int j = u / 640;
      int rem = u - j * 640;
      int m = rem / 5;
      int kp = (rem - m * 5) * 2;
      const float2 v = *(const float2*)(rp + (size_t)j * (DX * DY) + (size_t)(mc * 128 + m) * DY + kp);
      int row0 = j * DY + kp;
      R_s[(row0 * 128 + m) ^ ((row0 & 15) << 3)] = f2bf(v.x);
      int row1 = row0 + 1;
      R_s[(row1 * 128 + m) ^ ((row1 & 15) << 3)] = f2bf(v.y);
      if ((j & ~1) == kp) atomicAdd(&S_s[m], (j & 1) ? v.y : v.x);
    }
    __syncthreads();
    if (t < 128) S[(size_t)p * DX + mc * 128 + t] = S_s[t];
#pragma unroll
    for (int i = 0; i < 7; ++i) {
      int c = i * 256 + t;
      int row = c >> 4, sl = c & 15;
      uint4 v = make_uint4(0u, 0u, 0u, 0u);
      if (row < NJK) v = *(const uint4*)&R_s[(row * 128 + sl * 8) ^ ((row & 15) << 3)];
      *(uint4*)(R2p + (size_t)row * 1024 + mc * 128 + sl * 8) = v;
    }
  }
}

// ---------------------------------------------------------------------------
// P0a: for one 16-batch group, emit BOTH operands of K1 pre-split:
//  XHL [bl][kt(32)][m(1024)][8 slots x 16B] : record = [Ah k0..31 | Al k0..31]
//  XtHL[bl][kt(32)][p(1024)][8 slots x 16B] : same for X^T rows.
// ---------------------------------------------------------------------------
__launch_bounds__(256)
__global__ void p0_split(const float* __restrict__ X,
                         ushort_t* __restrict__ XHL, ushort_t* __restrict__ XtHL) {
  __shared__ float T[64][65];
  int blk = blockIdx.x;
  int bl = blk >> 8;  // local batch 0..15
  int tt = blk & 255;
  int r0 = (tt >> 4) << 6;  // X row block
  int c0 = (tt & 15) << 6;  // X col block
  const float* Xb = X + (size_t)bl * DX * DX;
  int t = threadIdx.x;
  int r = t >> 4, c = t & 15;
#pragma unroll
  for (int s = 0; s < 4; ++s) {
    const float4 v = *(const float4*)(Xb + (size_t)(r0 + r + 16 * s) * DX + c0 + c * 4);
    T[r + 16 * s][c * 4 + 0] = v.x;
    T[r + 16 * s][c * 4 + 1] = v.y;
    T[r + 16 * s][c * 4 + 2] = v.z;
    T[r + 16 * s][c * 4 + 3] = v.w;
  }
  __syncthreads();
  int s8 = t & 7;   // slot 0..7
  int rw = t >> 3;  // 0..31
  int isLo = s8 >> 2, q = s8 & 3;
#pragma unroll
  for (int ktl = 0; ktl < 2; ++ktl) {
#pragma unroll
    for (int sp = 0; sp < 2; ++sp) {
      int loc = rw + sp * 32;
      {
        unsigned short h[8];
#pragma unroll
        for (int e = 0; e < 8; ++e) {
          float x = T[loc][ktl * 32 + q * 8 + e];
          unsigned short hh = f2bf(x);
          h[e] = isLo ? f2bf(x - bf2f(hh)) : hh;
        }
        int kt = (c0 >> 5) + ktl;
        size_t off = (((size_t)bl * 32 + kt) * 1024 + (r0 + loc)) * 64 + s8 * 8;
        uint4 v;
        v.x = (unsigned)h[0] | ((unsigned)h[1] << 16);
        v.y = (unsigned)h[2] | ((unsigned)h[3] << 16);
        v.z = (unsigned)h[4] | ((unsigned)h[5] << 16);
        v.w = (unsigned)h[6] | ((unsigned)h[7] << 16);
        *(uint4*)(XHL + off) = v;
      }
      {
        unsigned short h[8];
#pragma unroll
        for (int e = 0; e < 8; ++e) {
          float x = T[ktl * 32 + q * 8 + e][loc];
          unsigned short hh = f2bf(x);
          h[e] = isLo ? f2bf(x - bf2f(hh)) : hh;
        }
        int kt = (r0 >> 5) + ktl;
        size_t off = (((size_t)bl * 32 + kt) * 1024 + (c0 + loc)) * 64 + s8 * 8;
        uint4 v;
        v.x = (unsigned)h[0] | ((unsigned)h[1] << 16);
        v.y = (unsigned)h[2] | ((unsigned)h[3] << 16);
        v.z = (unsigned)h[4] | ((unsigned)h[5] << 16);
        v.w = (unsigned)h[6] | ((unsigned)h[7] << 16);
        *(uint4*)(XtHL + off) = v;
      }
    }
  }
}

// ---------------------------------------------------------------------------
// K1: A[b]=X[b]@X[b], 3-pass split-bf16. 256x256 tile, BK=32, 8 waves (2x4),
// all staging via global_load_lds (front-loaded 8/thread/kt), counted
// vmcnt(8), raw barriers (no drain), setprio MFMA clusters.
// Epilogue 1: EXACT trace partial = <f32 acc, S[p,m]> -> part_tr[b*16+tile].
// Epilogue 2: Ah bf16 -> [p][b][m] via LDS transpose (coalesced).
// ---------------------------------------------------------------------------
__launch_bounds__(512, 2)
__global__ void k1_gemm(const ushort_t* __restrict__ XHL,
                        const ushort_t* __restrict__ XtHL,
                        const float* __restrict__ S,
                        ushort_t* __restrict__ Ahg,
                        float* __restrict__ part_tr, int bg) {
  __shared__ ushort_t lds[65536];  // 2 bufs x (A 16384 | B 16384) ushorts
  int wg = blockIdx.x;
  int gt = (wg & 7) * 32 + (wg >> 3);  // XCD-chunked: 2 batches per XCD
  int bl = gt >> 4, tile = gt & 15;
  int b = bg * 16 + bl;
  int m0 = (tile >> 2) << 8, p0 = (tile & 3) << 8;
  int t = threadIdx.x;
  int wv = t >> 6, lane = t & 63, l31 = lane & 31, hi8 = lane >> 5;
  int wm = (wv >> 2) << 7, wp = (wv & 3) << 6;

  f32x16 acc[4][2];
#pragma unroll
  for (int mi = 0; mi < 4; ++mi)
#pragma unroll
    for (int ni = 0; ni < 2; ++ni)
#pragma unroll
      for (int e = 0; e < 16; ++e) acc[mi][ni][e] = 0.f;

  int lam = lane >> 3;          // row-within-8
  int lsl = (lane & 7) ^ lam;   // inverse-swizzled source slot
  const ushort_t* Asrc = XHL + ((size_t)bl * 32 * 1024 + m0) * 64 + (size_t)lsl * 8;
  const ushort_t* Bsrc = XtHL + ((size_t)bl * 32 * 1024 + p0) * 64 + (size_t)lsl * 8;
  int ldsw = (t & ~63) * 8;  // wave-uniform ushort offset (wv*512)

  auto stage = [&](int kt) {
    int buf = (kt & 1) << 15;
    size_t ko = (size_t)kt * 65536;
#pragma unroll
    for (int i = 0; i < 4; ++i) {
      int rr = (i << 6) + (wv << 3) + lam;
      gload16(Asrc + ko + (size_t)rr * 64, &lds[buf + (i << 12) + ldsw]);
    }
#pragma unroll
    for (int i = 0; i < 4; ++i) {
      int rr = (i << 6) + (wv << 3) + lam;
      gload16(Bsrc + ko + (size_t)rr * 64, &lds[buf + 16384 + (i << 12) + ldsw]);
    }
  };

  stage(0);
#pragma unroll 1
  for (int kt = 0; kt < 32; ++kt) {
    int buf = (kt & 1) << 15;
    if (kt < 31) {
      stage(kt + 1);
      VMCNT8;
    } else {
      VMCNT0;
    }
    __builtin_amdgcn_s_barrier();
    CFENCE;
#pragma unroll
    for (int kc = 0; kc < 2; ++kc) {
      short8 bh[2], blo[2];
#pragma unroll
      for (int ni = 0; ni < 2; ++ni) {
        int p = wp + (ni << 5) + l31;
        int rowb = buf + 16384 + p * 64;
        bh[ni] = *(const short8*)&lds[rowb + (((kc * 2 + hi8) ^ (p & 7)) << 3)];
        blo[ni] = *(const short8*)&lds[rowb + (((4 + kc * 2 + hi8) ^ (p & 7)) << 3)];
      }
#pragma unroll
      for (int mh = 0; mh < 2; ++mh) {
        short8 ah[2], al[2];
#pragma unroll
        for (int mi2 = 0; mi2 < 2; ++mi2) {
          int m = wm + ((mh * 2 + mi2) << 5) + l31;
          int rowa = buf + m * 64;
          ah[mi2] = *(const short8*)&lds[rowa + (((kc * 2 + hi8) ^ (m & 7)) << 3)];
          al[mi2] = *(const short8*)&lds[rowa + (((4 + kc * 2 + hi8) ^ (m & 7)) << 3)];
        }
        __builtin_amdgcn_s_setprio(1);
#pragma unroll
        for (int mi2 = 0; mi2 < 2; ++mi2) {
          int mi = mh * 2 + mi2;
#pragma unroll
          for (int ni = 0; ni < 2; ++ni) {
            acc[mi][ni] = __builtin_amdgcn_mfma_f32_32x32x16_bf16(ah[mi2], bh[ni], acc[mi][ni], 0, 0, 0);
            acc[mi][ni] = __builtin_amdgcn_mfma_f32_32x32x16_bf16(ah[mi2], blo[ni], acc[mi][ni], 0, 0, 0);
            acc[mi][ni] = __builtin_amdgcn_mfma_f32_32x32x16_bf16(al[mi2], bh[ni], acc[mi][ni], 0, 0, 0);
          }
        }
        __builtin_amdgcn_s_setprio(0);
      }
    }
    CFENCE;
    __builtin_amdgcn_s_barrier();
  }

  // ---- epilogue 1: EXACT trace partial from f32 accumulator ----
  float tracc = 0.f;
#pragma unroll
  for (int mi = 0; mi < 4; ++mi)
#pragma unroll
    for (int ni = 0; ni < 2; ++ni) {
      int p = p0 + wp + (ni << 5) + l31;
#pragma unroll
      for (int rg = 0; rg < 4; ++rg) {
        int m = m0 + wm + (mi << 5) + 8 * rg + 4 * hi8;
        const float4 sv = *(const float4*)(S + (size_t)p * DX + m);
        tracc += acc[mi][ni][rg * 4 + 0] * sv.x + acc[mi][ni][rg * 4 + 1] * sv.y +
                 acc[mi][ni][rg * 4 + 2] * sv.z + acc[mi][ni][rg * 4 + 3] * sv.w;
      }
    }
#pragma unroll
  for (int off = 32; off > 0; off >>= 1) tracc += __shfl_xor(tracc, off, 64);
  __syncthreads();
  if (lane == 0) ((float*)lds)[wv] = tracc;
  __syncthreads();
  if (t == 0) {
    float s = 0.f;
    for (int i = 0; i < 8; ++i) s += ((float*)lds)[i];
    part_tr[b * 16 + tile] = s;
  }
  __syncthreads();

  // ---- epilogue 2: Ah -> LDS [p][m] (swizzled) -> coalesced 16B stores ----
#pragma unroll
  for (int mi = 0; mi < 4; ++mi)
#pragma unroll
    for (int ni = 0; ni < 2; ++ni) {
      int p = wp + (ni << 5) + l31;
#pragma unroll
      for (int rg = 0; rg < 4; ++rg) {
        int m = wm + (mi << 5) + 8 * rg + 4 * hi8;
        unsigned int h0 = f2bf(acc[mi][ni][rg * 4 + 0]);
        unsigned int h1 = f2bf(acc[mi][ni][rg * 4 + 1]);
        unsigned int h2 = f2bf(acc[mi][ni][rg * 4 + 2]);
        unsigned int h3 = f2bf(acc[mi][ni][rg * 4 + 3]);
        int idx = p * 256 + (((m >> 3) ^ (p & 7)) << 3) + (m & 7);
        *(uint2*)&lds[idx] = make_uint2(h0 | (h1 << 16), h2 | (h3 << 16));
      }
    }
  __syncthreads();
#pragma unroll
  for (int i = 0; i < 16; ++i) {
    int cc = i * 512 + t;
    int row = cc >> 5, sl = cc & 31;
    int idx = row * 256 + ((sl ^ (row & 7)) << 3);
    uint4 v = *(const uint4*)&lds[idx];
    *(uint4*)(Ahg + ((size_t)(p0 + row) * NB + b) * DX + m0 + sl * 8) = v;
  }
}

// ---------------------------------------------------------------------------
// K2: numerator. One block per p: C[b,jk] += Ah[b,m]*R2[jk,m], K=1024.
// Pure gload16 staging from R2+Ahg, full dbuf, uniform 11 loads/thread/chunk,
// counted vmcnt(11), raw barriers, setprio MFMA.
// ---------------------------------------------------------------------------
__launch_bounds__(256)
__global__ void k2_contract(const ushort_t* __restrict__ R2,
                            const ushort_t* __restrict__ Ahg,
                            float* __restrict__ part_rho) {
  __shared__ ushort_t lds[45056];  // 2 bufs x (A 8192 | B 14336) ushorts
  int p = blockIdx.x;
  int t = threadIdx.x;
  int wv = t >> 6, lane = t & 63, lr = lane & 15, lg = lane >> 4;
  const ushort_t* R2p = R2 + (size_t)p * (112 * 1024);
  const ushort_t* Ahp = Ahg + (size_t)p * (NB * DX);

  f32x4 acc[7];
#pragma unroll
  for (int n = 0; n < 7; ++n)
#pragma unroll
    for (int i = 0; i < 4; ++i) acc[n][i] = 0.f;

  auto stage = [&](int mc) {
    int buf = (mc & 1) * 22528;
#pragma unroll
    for (int i = 0; i < 4; ++i) {
      int c = i * 256 + t;
      int br = c >> 4, psl = c & 15;
      int lsl = psl ^ (br & 15);
      gload16(Ahp + (size_t)br * DX + mc * 128 + lsl * 8,
              &lds[buf + (i * 256 + (t & ~63)) * 8]);
    }
#pragma unroll
    for (int i = 0; i < 7; ++i) {
      int c = i * 256 + t;
      int row = c >> 4, psl = c & 15;
      int lsl = psl ^ (row & 15);
      gload16(R2p + (size_t)row * 1024 + mc * 128 + lsl * 8,
              &lds[buf + 8192 + (i * 256 + (t & ~63)) * 8]);
    }
  };

  stage(0);
#pragma unroll 1
  for (int mc = 0; mc < 8; ++mc) {
    int buf = (mc & 1) * 22528;
    if (mc < 7) {
      stage(mc + 1);
      VMCNT11;
    } else {
      VMCNT0;
    }
    __builtin_amdgcn_s_barrier();
    CFENCE;
#pragma unroll
    for (int s = 0; s < 4; ++s) {
      int kk = s * 32 + lg * 8;
      int ra = 16 * wv + lr;
      short8 af = *(const short8*)&lds[buf + ((ra * 128 + kk) ^ ((ra & 15) << 3))];
      __builtin_amdgcn_s_setprio(1);
#pragma unroll
      for (int n = 0; n < 7; ++n) {
        int rb = 16 * n + lr;
        short8 bf = *(const short8*)&lds[buf + 8192 + ((rb * 128 + kk) ^ ((rb & 15) << 3))];
        acc[n] = __builtin_amdgcn_mfma_f32_16x16x32_bf16(af, bf, acc[n], 0, 0, 0);
      }
      __builtin_amdgcn_s_setprio(0);
    }
    CFENCE;
    __builtin_amdgcn_s_barrier();
  }
#pragma unroll
  for (int n = 0; n < 7; ++n) {
    int col = 16 * n + lr;
    if (col < NJK) {
#pragma unroll
      for (int i = 0; i < 4; ++i) {
        int b_ = 16 * wv + lg * 4 + i;
        part_rho[((size_t)p * NB + b_) * NJK + col] = acc[n][i];
      }
    }
  }
}

// ---------------------------------------------------------------------------
// K3a: partial p-reduction; K3b: finish + divide by EXACT trace.
// ---------------------------------------------------------------------------
__launch_bounds__(128)
__global__ void k3a(const float* __restrict__ part_rho, float* __restrict__ ws2) {
  int blk = blockIdx.x;  // 128 = 64 b x 2 halves
  int b = blk >> 1, h = blk & 1;
  int t = threadIdx.x;
  if (t >= NJK) return;
  float s = 0.f;
  for (int pp = 0; pp < 512; ++pp)
    s += part_rho[((size_t)(h * 512 + pp) * NB + b) * NJK + t];
  ws2[(size_t)(h * NB + b) * 128 + t] = s;
}

__launch_bounds__(128)
__global__ void k3b(const float* __restrict__ ws2, const float* __restrict__ part_tr,
                    float* __restrict__ out) {
  int b = blockIdx.x;
  int t = threadIdx.x;
  float tr = 0.f;
#pragma unroll
  for (int i = 0; i < 16; ++i) tr += part_tr[b * 16 + i];
  if (t < NJK) {
    float v = ws2[(size_t)b * 128 + t] + ws2[(size_t)(NB + b) * 128 + t];
    out[b * NJK + t] = v / tr;
  }
}

extern "C" void kernel_launch(void* const* d_in, const int* in_sizes, int n_in,
                              void* d_out, int out_size, void* d_ws, size_t ws_size,
                              hipStream_t stream) {
  const float* X = (const float*)d_in[0];
  const float* rho = (const float*)d_in[1];
  float* out = (float*)d_out;
  char* ws = (char*)d_ws;

  const size_t MB = 1048576ull;
  ushort_t* XHL = (ushort_t*)(ws);              // 64 MiB (per 16-batch group)
  ushort_t* XtHL = (ushort_t*)(ws + 64 * MB);   // 64 MiB
  ushort_t* Ahg = (ushort_t*)(ws + 128 * MB);   // 128 MiB
  ushort_t* R2 = (ushort_t*)(ws + 256 * MB);    // 224 MiB
  float* S = (float*)(ws + 480 * MB);           // 4 MiB
  float* part_tr = (float*)(ws + 484 * MB);     // 4 KiB
  float* part_rho = (float*)(ws);               // 26 MiB, overlays XHL (dead after K1s)
  float* ws2 = (float*)(ws + 32 * MB);          // 64 KiB, past part_rho
  size_t need = 484 * MB + 65536;
  if (ws_size < need) return;

  hipLaunchKernelGGL(p0_rho, dim3(1024), dim3(256), 0, stream, rho, R2, S);
  for (int g = 0; g < 4; ++g) {
    hipLaunchKernelGGL(p0_split, dim3(4096), dim3(256), 0, stream,
                       X + (size_t)g * 16 * DX * DX, XHL, XtHL);
    hipLaunchKernelGGL(k1_gemm, dim3(256), dim3(512), 0, stream, XHL, XtHL, S, Ahg, part_tr, g);
  }
  hipLaunchKernelGGL(k2_contract, dim3(1024), dim3(256), 0, stream, R2, Ahg, part_rho);
  hipLaunchKernelGGL(k3a, dim3(128), dim3(128), 0, stream, part_rho, ws2);
  hipLaunchKernelGGL(k3b, dim3(64), dim3(128), 0, stream, ws2, part_tr, out);
}